// Round 6
// baseline (2159.515 us; speedup 1.0000x reference)
//
#include <hip/hip_runtime.h>
#include <math.h>

// Residual SF-DiVeQ (N=65536, D=64, C=4, K=1024) — bit-exact numpy-fp32 argmin.
// R6: row state moves to LDS, TRANSPOSED rzT[d][row] (16KB/block).
//  - inner read rzT[d][lane]: banks lane%32 (2-way, free), compile-time offset
//  - register file holds only 8 accumulators -> launch_bounds(256,8), VGPR<=64
//  - codebook stays wave-uniform s_load (SMEM pipe parallel to VALU+LDS)
//  - numerics IDENTICAL to R3 (passed): fmaf d-ascending chains, pairwise srr,
//    (srr - 2*dot) + cn rounding order, ascending-k strict < ties,
//    single-rounded fp32 rem subtract.
// FMA floor: 1.72e10 FMA / 78.6 T-FMA/s = 219 us.

#define N_PTS 65536
#define DIM 64
#define NCB 4
#define KCB 1024
#define WAVES 4
#define KPART (KCB / WAVES)   // 256
#define ROWS 64               // rows per block (= lanes)

typedef float f32x8 __attribute__((ext_vector_type(8)));

// ---------------- prep: cn[c][k] = numpy-pairwise ||c_k||^2 (fp32), zero counts
__global__ __launch_bounds__(256) void prep_kernel(const float* __restrict__ cb,
    float* __restrict__ cnp, int* __restrict__ counts)
{
#pragma clang fp contract(off)
    int t = blockIdx.x * 256 + threadIdx.x;       // grid 16 -> 4096 = C*K
    const float* row = cb + (size_t)t * DIM;
    float pr[8];
#pragma unroll
    for (int j = 0; j < 8; ++j) { float v = row[j]; pr[j] = v * v; }
#pragma unroll
    for (int i = 8; i < DIM; i += 8)
#pragma unroll
        for (int j = 0; j < 8; ++j) { float v = row[i + j]; pr[j] += v * v; }
    cnp[t] = ((pr[0] + pr[1]) + (pr[2] + pr[3])) + ((pr[4] + pr[5]) + (pr[6] + pr[7]));
    counts[t] = 0;
}

// ---------------- fused residual-VQ ------------------------------------------
// block: 256 thr = 4 waves; wave w scans k in [w*256,(w+1)*256); lane = row.
// Residual lives in LDS transposed: rzT[d][row].
__global__ __launch_bounds__(256, 8) void rvq_kernel(
    const float* __restrict__ z, const float* __restrict__ cbook,
    const float* __restrict__ cnp, int* __restrict__ idxA)
{
#pragma clang fp contract(off)
    __shared__ float rzT[DIM][ROWS];              // 16 KB
    __shared__ float lm[WAVES][ROWS];
    __shared__ int   li[WAVES][ROWS];

    int lane = threadIdx.x & 63;
    int w = __builtin_amdgcn_readfirstlane(threadIdx.x >> 6);  // SGPR-uniform
    int n = blockIdx.x * ROWS + lane;
    int kbase = w * KPART;

    // fill rzT: wave w writes d-range [w*16, w*16+16) of its lane's row
    {
        const float4* zr = (const float4*)(z + (size_t)n * DIM + w * 16);
#pragma unroll
        for (int j = 0; j < 4; ++j) {
            float4 v = zr[j];
            rzT[w * 16 + j * 4 + 0][lane] = v.x;
            rzT[w * 16 + j * 4 + 1][lane] = v.y;
            rzT[w * 16 + j * 4 + 2][lane] = v.z;
            rzT[w * 16 + j * 4 + 3][lane] = v.w;
        }
    }
    __syncthreads();

    for (int c = 0; c < NCB; ++c) {
        // srr = numpy-pairwise sum of rz^2 (8 accumulators stride-8, fixed tree)
        f32x8 pr;
#pragma unroll
        for (int j = 0; j < 8; ++j) { float v = rzT[j][lane]; pr[j] = v * v; }
#pragma unroll
        for (int i = 8; i < DIM; i += 8)
#pragma unroll
            for (int j = 0; j < 8; ++j) { float v = rzT[i + j][lane]; pr[j] += v * v; }
        float srr = ((pr[0] + pr[1]) + (pr[2] + pr[3])) + ((pr[4] + pr[5]) + (pr[6] + pr[7]));

        const float* cb = cbook + (size_t)c * KCB * DIM;
        const float* cn = cnp + c * KCB;

        float m1 = 3.4028235e38f; int ix = kbase;
        for (int kk = 0; kk < KPART; kk += 8) {   // 8 sgemm-style k-chains
            int k0 = kbase + kk;
            const float* c0 = cb + (size_t)k0 * DIM;   // uniform -> s_load base
            f32x8 a = (f32x8)0.0f;
#pragma unroll
            for (int d = 0; d < DIM; ++d) {       // d ascending: exact chain order
                float rzd = rzT[d][lane];         // ds_read_b32, imm offset
#pragma unroll
                for (int j = 0; j < 8; ++j)
                    a[j] = fmaf(rzd, c0[j * DIM + d], a[j]);
            }
#pragma unroll
            for (int j = 0; j < 8; ++j) {         // ascending k, strict <
                float t1 = 2.0f * a[j];           // exact
                float t2 = srr - t1;              // ref rounding order
                float dd = t2 + cn[k0 + j];
                if (dd < m1) { m1 = dd; ix = k0 + j; }
            }
        }
        lm[w][lane] = m1; li[w][lane] = ix;
        __syncthreads();

        // merge partitions ascending w (= ascending k), strict < (numpy ties)
        float bm = lm[0][lane]; int bx = li[0][lane];
#pragma unroll
        for (int s = 1; s < WAVES; ++s) {
            float v = lm[s][lane]; int xi = li[s][lane];
            if (v < bm) { bm = v; bx = xi; }
        }
        if (w == 0) idxA[c * N_PTS + n] = bx;

        // rem update: wave w handles d-range [w*16, w*16+16) of lane's row.
        // single-rounded fp32 subtract (bit-exact vs scan carry).
        {
            const float4* q4 = (const float4*)(cb + (size_t)bx * DIM + w * 16);
#pragma unroll
            for (int j = 0; j < 4; ++j) {
                float4 q = q4[j];                  // per-lane gather (L2-hot)
                int d = w * 16 + j * 4;
                rzT[d + 0][lane] = rzT[d + 0][lane] - q.x;
                rzT[d + 1][lane] = rzT[d + 1][lane] - q.y;
                rzT[d + 2][lane] = rzT[d + 2][lane] - q.z;
                rzT[d + 3][lane] = rzT[d + 3][lane] - q.w;
            }
        }
        __syncthreads();
    }
}

// ---------------- epilogue: z_q (fp64; threshold ~2% of magnitude) -----------
__global__ __launch_bounds__(256) void zq_kernel(
    const float* __restrict__ z, const float* __restrict__ noise,
    const float* __restrict__ cbase, const int* __restrict__ idxA,
    float* __restrict__ out)
{
    int lane = threadIdx.x & 63;
    int n = blockIdx.x * 4 + (threadIdx.x >> 6);   // grid 16384
    size_t e = (size_t)n * DIM + lane;
    double zd = z[e];
    double rd = zd;
#pragma unroll
    for (int cc = 0; cc < NCB; ++cc) {
        int id = idxA[cc * N_PTS + n];
        rd -= (double)cbase[((size_t)cc * KCB + id) * DIM + lane];
    }
    double dir = -rd;                               // z_hard - z
    double rv = fma(1e-3, (double)noise[e], dir);
    double srv = rv * rv, sdir = dir * dir;
#pragma unroll
    for (int off = 32; off >= 1; off >>= 1) {
        srv  += __shfl_xor(srv, off);
        sdir += __shfl_xor(sdir, off);
    }
    double em = sqrt(sdir);
    double nn = sqrt(srv); nn = nn > 1e-12 ? nn : 1e-12;
    out[e] = (float)(zd + em * rv / nn);
}

// ---------------- histogram + idx output (as float32) ------------------------
__global__ __launch_bounds__(256) void hist_kernel(
    const int* __restrict__ idxA, float* __restrict__ out_idx, int* __restrict__ counts)
{
    int t = blockIdx.x * 256 + threadIdx.x;        // C*N, grid 1024
    int v = idxA[t];
    out_idx[t] = (float)v;
    atomicAdd(&counts[(t >> 16) * KCB + v], 1);
}

// ---------------- perplexity -------------------------------------------------
__global__ __launch_bounds__(1024) void perp_kernel(const int* __restrict__ counts,
                                                    float* __restrict__ out)
{
    __shared__ double red[16];
    int tid = threadIdx.x, lane = tid & 63, w = tid >> 6;
    for (int c = 0; c < NCB; ++c) {
        double p = (double)counts[c * KCB + tid] / (double)N_PTS;
        double v = p * log(p + 1e-10);
#pragma unroll
        for (int off = 32; off >= 1; off >>= 1) v += __shfl_xor(v, off);
        if (lane == 0) red[w] = v;
        __syncthreads();
        if (tid == 0) {
            double ssum = 0.0;
            for (int i = 0; i < 16; ++i) ssum += red[i];
            out[c] = (float)exp(-ssum);
        }
        __syncthreads();
    }
}

extern "C" void kernel_launch(void* const* d_in, const int* in_sizes, int n_in,
                              void* d_out, int out_size, void* d_ws, size_t ws_size,
                              hipStream_t stream)
{
    const float* z     = (const float*)d_in[0];
    const float* cbook = (const float*)d_in[1];   // [C,K,D]
    const float* noise = (const float*)d_in[2];
    float* out = (float*)d_out;
    char* ws = (char*)d_ws;

    // ws layout (~1.1 MB)
    int*   idxA   = (int*)  (ws);                  // C*N i32   1,048,576 B
    float* cnp    = (float*)(ws + 1048576);        // C*K f32      16,384
    int*   counts = (int*)  (ws + 1064960);        // C*K i32      16,384

    prep_kernel<<<16, 256, 0, stream>>>(cbook, cnp, counts);
    rvq_kernel<<<N_PTS / ROWS, 256, 0, stream>>>(z, cbook, cnp, idxA);
    zq_kernel<<<N_PTS / 4, 256, 0, stream>>>(z, noise, cbook, idxA, out);
    hist_kernel<<<NCB * N_PTS / 256, 256, 0, stream>>>(
        idxA, out + (size_t)N_PTS * DIM, counts);
    perp_kernel<<<1, 1024, 0, stream>>>(
        counts, out + (size_t)N_PTS * DIM + (size_t)NCB * N_PTS);
}

// Round 7
// 1002.165 us; speedup vs baseline: 2.1549x; 2.1549x over previous
//
#include <hip/hip_runtime.h>
#include <math.h>

// Residual SF-DiVeQ (N=65536, D=64, C=4, K=1024) — bit-exact numpy-fp32 argmin.
// R7: lane = CODEWORD structure. Each lane holds one codeword (64 floats in
// 16 named float4 VGPRs, loaded once per block); rows stream as wave-uniform
// (s_load) operands; inner loop = 64 pure v_fma. Exact-d2 u64 (dd,k) packing
// makes min-reduce = numpy first-index argmin (dd>0 guaranteed by data scale).
// Aux per stage: uprr kernel = single-rounded fp32 rem update + exact numpy
// pairwise srr via shfl (sequential stride-8 chains + fixed combine tree).
// FMA floor: 1.72e10 FMA / 78.6 T-FMA/s = 219 us.

#define N_PTS 65536
#define DIM 64
#define NCB 4
#define KCB 1024
#define PARTS 4
#define KP (KCB / PARTS)        // 256 codewords per partition (4 waves x 64)
#define RB 512                  // row-blocks per partition
#define RPB (N_PTS / RB)        // 128 rows per dist block

typedef unsigned long long u64;

// ---------------- prep: cn[c][k] = numpy-pairwise ||c_k||^2, zero counts -----
__global__ __launch_bounds__(256) void prep_kernel(const float* __restrict__ cb,
    float* __restrict__ cnp, int* __restrict__ counts)
{
#pragma clang fp contract(off)
    int t = blockIdx.x * 256 + threadIdx.x;       // grid 16 -> 4096 = C*K
    const float* row = cb + (size_t)t * DIM;
    float pr[8];
#pragma unroll
    for (int j = 0; j < 8; ++j) { float v = row[j]; pr[j] = v * v; }
#pragma unroll
    for (int i = 8; i < DIM; i += 8)
#pragma unroll
        for (int j = 0; j < 8; ++j) { float v = row[i + j]; pr[j] += v * v; }
    cnp[t] = ((pr[0] + pr[1]) + (pr[2] + pr[3])) + ((pr[4] + pr[5]) + (pr[6] + pr[7]));
    counts[t] = 0;
}

// ---------------- uprr: rem = src - cb[ix] (fp32 single-rounded) + srr -------
// One wave per row, lane = dim. srr replicates numpy pairwise EXACTLY:
// pr[j] = sq[j] + sq[j+8] + ... (sequential chain, i ascending), then
// ((p0+p1)+(p2+p3))+((p4+p5)+(p6+p7)) via xor-tree (fp add commutative-safe).
__global__ __launch_bounds__(256) void uprr_kernel(
    const float* __restrict__ src, const float* __restrict__ cbc,
    const int* __restrict__ ixp, float* __restrict__ rem, float* __restrict__ srr)
{
#pragma clang fp contract(off)
    int lane = threadIdx.x & 63;
    int n = blockIdx.x * 4 + (threadIdx.x >> 6);   // grid 16384
    size_t e = (size_t)n * DIM + lane;
    float r = src[e];
    if (cbc) {
        int ix = ixp[n];                            // wave-uniform broadcast
        r = r - cbc[(size_t)ix * DIM + lane];       // single rounding
        rem[e] = r;
    }
    float sq = r * r;
    float pr = sq;
#pragma unroll
    for (int i = 1; i < 8; ++i) pr += __shfl(sq, (lane & 7) + 8 * i);
    pr += __shfl_xor(pr, 1);
    pr += __shfl_xor(pr, 2);
    pr += __shfl_xor(pr, 4);
    if (lane == 0) srr[n] = pr;
}

// ---------------- dist: lane = codeword, rows streamed wave-uniform ----------
#define FMA4(RA, QA) \
    acc = fmaf(RA.x, QA.x, acc); acc = fmaf(RA.y, QA.y, acc); \
    acc = fmaf(RA.z, QA.z, acc); acc = fmaf(RA.w, QA.w, acc);

__global__ __launch_bounds__(256, 3) void dist_kernel(
    const float* __restrict__ src, const float* __restrict__ cbc,
    const float* __restrict__ cnc, const float* __restrict__ srr,
    u64* __restrict__ pm)
{
#pragma clang fp contract(off)
    int lane = threadIdx.x & 63;
    int wv = threadIdx.x >> 6;
    int part = blockIdx.x & 3;
    int rb = blockIdx.x >> 2;
    int k = part * KP + wv * 64 + lane;            // this lane's codeword

    const float4* cw = (const float4*)(cbc + (size_t)k * DIM);
    float4 q0 = cw[0],  q1 = cw[1],  q2 = cw[2],  q3 = cw[3];
    float4 q4 = cw[4],  q5 = cw[5],  q6 = cw[6],  q7 = cw[7];
    float4 q8 = cw[8],  q9 = cw[9],  q10 = cw[10], q11 = cw[11];
    float4 q12 = cw[12], q13 = cw[13], q14 = cw[14], q15 = cw[15];
    float cn = cnc[k];
    int s = part * 4 + wv;                          // partial slot (k ascending)

    for (int r = 0; r < RPB; ++r) {
        int n = rb * RPB + r;                       // uniform row id
        const float4* rr = (const float4*)(src + (size_t)n * DIM);
        float sr = srr[n];
        float acc = 0.0f;
        float4 ra;
        ra = rr[0];  FMA4(ra, q0);   ra = rr[1];  FMA4(ra, q1);
        ra = rr[2];  FMA4(ra, q2);   ra = rr[3];  FMA4(ra, q3);
        ra = rr[4];  FMA4(ra, q4);   ra = rr[5];  FMA4(ra, q5);
        ra = rr[6];  FMA4(ra, q6);   ra = rr[7];  FMA4(ra, q7);
        ra = rr[8];  FMA4(ra, q8);   ra = rr[9];  FMA4(ra, q9);
        ra = rr[10]; FMA4(ra, q10);  ra = rr[11]; FMA4(ra, q11);
        ra = rr[12]; FMA4(ra, q12);  ra = rr[13]; FMA4(ra, q13);
        ra = rr[14]; FMA4(ra, q14);  ra = rr[15]; FMA4(ra, q15);

        float t1 = 2.0f * acc;                      // exact
        float t2 = sr - t1;                         // ref rounding order
        float dd = t2 + cn;                         // dd > 0 (||rem||^2 ~ 60)
        u64 key = ((u64)__float_as_uint(dd) << 32) | (unsigned)k;
#pragma unroll
        for (int off = 1; off < 64; off <<= 1) {
            u64 o = __shfl_xor(key, off);
            if (o < key) key = o;                   // u64 min = argmin+ties
        }
        if (lane == 0) pm[(size_t)s * N_PTS + n] = key;
    }
}

// ---------------- merge 16 per-wave partials (u64 min = exact ties) ----------
__global__ __launch_bounds__(256) void merge_kernel(
    const u64* __restrict__ pm, int* __restrict__ idx)
{
    int n = blockIdx.x * 256 + threadIdx.x;        // grid 256
    u64 m = pm[n];
#pragma unroll
    for (int s = 1; s < 16; ++s) {
        u64 v = pm[(size_t)s * N_PTS + n];
        if (v < m) m = v;
    }
    idx[n] = (int)(unsigned)(m & 0xffffffffu);
}

// ---------------- epilogue: z_q (fp64; threshold ~2% of magnitude) -----------
__global__ __launch_bounds__(256) void zq_kernel(
    const float* __restrict__ z, const float* __restrict__ noise,
    const float* __restrict__ cbase, const int* __restrict__ idxA,
    float* __restrict__ out)
{
    int lane = threadIdx.x & 63;
    int n = blockIdx.x * 4 + (threadIdx.x >> 6);   // grid 16384
    size_t e = (size_t)n * DIM + lane;
    double zd = z[e];
    double rd = zd;
#pragma unroll
    for (int cc = 0; cc < NCB; ++cc) {
        int id = idxA[cc * N_PTS + n];
        rd -= (double)cbase[((size_t)cc * KCB + id) * DIM + lane];
    }
    double dir = -rd;                               // z_hard - z
    double rv = fma(1e-3, (double)noise[e], dir);
    double srv = rv * rv, sdir = dir * dir;
#pragma unroll
    for (int off = 32; off >= 1; off >>= 1) {
        srv  += __shfl_xor(srv, off);
        sdir += __shfl_xor(sdir, off);
    }
    double em = sqrt(sdir);
    double nn = sqrt(srv); nn = nn > 1e-12 ? nn : 1e-12;
    out[e] = (float)(zd + em * rv / nn);
}

// ---------------- histogram + idx output (as float32) ------------------------
__global__ __launch_bounds__(256) void hist_kernel(
    const int* __restrict__ idxA, float* __restrict__ out_idx, int* __restrict__ counts)
{
    int t = blockIdx.x * 256 + threadIdx.x;        // C*N, grid 1024
    int v = idxA[t];
    out_idx[t] = (float)v;
    atomicAdd(&counts[(t >> 16) * KCB + v], 1);
}

// ---------------- perplexity -------------------------------------------------
__global__ __launch_bounds__(1024) void perp_kernel(const int* __restrict__ counts,
                                                    float* __restrict__ out)
{
    __shared__ double red[16];
    int tid = threadIdx.x, lane = tid & 63, w = tid >> 6;
    for (int c = 0; c < NCB; ++c) {
        double p = (double)counts[c * KCB + tid] / (double)N_PTS;
        double v = p * log(p + 1e-10);
#pragma unroll
        for (int off = 32; off >= 1; off >>= 1) v += __shfl_xor(v, off);
        if (lane == 0) red[w] = v;
        __syncthreads();
        if (tid == 0) {
            double ssum = 0.0;
            for (int i = 0; i < 16; ++i) ssum += red[i];
            out[c] = (float)exp(-ssum);
        }
        __syncthreads();
    }
}

extern "C" void kernel_launch(void* const* d_in, const int* in_sizes, int n_in,
                              void* d_out, int out_size, void* d_ws, size_t ws_size,
                              hipStream_t stream)
{
    const float* z     = (const float*)d_in[0];
    const float* cbook = (const float*)d_in[1];   // [C,K,D]
    const float* noise = (const float*)d_in[2];
    float* out = (float*)d_out;
    char* ws = (char*)d_ws;

    // rem scratch = d_out's z_q region (16MB), overwritten by zq at the end.
    float* rem = out;

    // ws layout (~9.3 MB)
    u64*   pm     = (u64*)  (ws);                  // 16*N u64   8,388,608 B
    int*   idxA   = (int*)  (ws + 8388608);        // C*N i32    1,048,576
    float* cnp    = (float*)(ws + 9437184);        // C*K f32       16,384
    int*   counts = (int*)  (ws + 9453568);        // C*K i32       16,384
    float* srr    = (float*)(ws + 9469952);        // N f32        262,144

    prep_kernel<<<16, 256, 0, stream>>>(cbook, cnp, counts);

    for (int c = 0; c < NCB; ++c) {
        const float* cb_prev = (c == 0) ? nullptr : cbook + (size_t)(c - 1) * KCB * DIM;
        const int*   ix_prev = (c == 0) ? nullptr : idxA + (size_t)(c - 1) * N_PTS;
        const float* usrc    = (c <= 1) ? z : rem;     // uprr input
        const float* dsrc    = (c == 0) ? z : rem;     // dist input
        uprr_kernel<<<N_PTS / 4, 256, 0, stream>>>(usrc, cb_prev, ix_prev, rem, srr);
        dist_kernel<<<PARTS * RB, 256, 0, stream>>>(
            dsrc, cbook + (size_t)c * KCB * DIM, cnp + c * KCB, srr, pm);
        merge_kernel<<<N_PTS / 256, 256, 0, stream>>>(pm, idxA + (size_t)c * N_PTS);
    }

    zq_kernel<<<N_PTS / 4, 256, 0, stream>>>(z, noise, cbook, idxA, out);
    hist_kernel<<<NCB * N_PTS / 256, 256, 0, stream>>>(
        idxA, out + (size_t)N_PTS * DIM, counts);
    perp_kernel<<<1, 1024, 0, stream>>>(
        counts, out + (size_t)N_PTS * DIM + (size_t)NCB * N_PTS);
}